// Round 8
// baseline (301.760 us; speedup 1.0000x reference)
//
#include <hip/hip_runtime.h>
#include <hip/hip_cooperative_groups.h>
#include <math.h>

namespace cg = cooperative_groups;

// OLE loss on MI355X — single cooperative kernel.
// ||X_c||* = trace(sqrt(G_c)), G_c = X_c^T X_c (128x128).
// Phases (grid.sync between): [gram | CE] -> Gall -> Newton-Schulz -> final.
// NS: Y,M split bf16 (hi+lo ~2^-17), Z single bf16; Frobenius normalization;
// scaled-NS coefficient ladder (9 iters); trace anchored on fp32 G.
// R8: phase (c) uses M as shared A-operand (Y'=M*Y, Z'=M*Z; iterates
// commute) -> 88 vs 120 b128 frag reads/wave/iter.

#define N_ROWS 8192
#define DIM    128
#define NCLS   64
#define NMAT   65
#define NITER  9
#define EPSN   2e-4f
#define LAMBDA_ 0.25f
#define DELTA_  1.0f

typedef __attribute__((ext_vector_type(8))) short s16x8;  // 8 bf16 = 4 VGPR
typedef __attribute__((ext_vector_type(4))) short s16x4;  // 4 bf16
typedef __attribute__((ext_vector_type(4))) float f32x4;

// Scaled-NS ladder: M_k = C1[k]*I - C2[k]*W, C1 = 1.5*sqrt(t), C2 = 0.5*t^1.5.
// t = [2.9, 2.758, 2.13, 1.868, 1.264, 1,1,1,1]; u = t*w, w' = u(1.5-u/2)^2
// stays in (0,1] for u in (0,3) -> sign-safe; final t=1 steps polish w->1.
static __device__ const float NS_C1[NITER] =
  {2.554408f, 2.491084f, 2.189178f, 2.050122f, 1.686417f, 1.5f, 1.5f, 1.5f, 1.5f};
static __device__ const float NS_C2[NITER] =
  {2.469261f, 2.290137f, 1.554316f, 1.276543f, 0.710544f, 0.5f, 0.5f, 0.5f, 0.5f};

__device__ __forceinline__ unsigned short f2bf(float f) {   // RNE
  unsigned u = __float_as_uint(f);
  u = (u + 0x7FFFu + ((u >> 16) & 1u)) >> 16;
  return (unsigned short)u;
}
__device__ __forceinline__ float bf2f(unsigned short h) {
  return __uint_as_float(((unsigned)h) << 16);
}

// bf16 LDS: element (i,j) at short-index i*128 + (((j>>3)^(i&15))<<3) + (j&7)
// 16B-group XOR swizzle -> all b128/b64 frag accesses 2-way per bank (free).
__device__ __forceinline__ int swz_idx(int i, int j) {
  return i * 128 + (((j >> 3) ^ (i & 15)) << 3) + (j & 7);
}

// MFMA 16x16x32 A/B fragment: lane holds 8 contiguous k at row (lane&15),
// kgroup = 4*kstep + (lane>>4).  Symmetric iterates: same loader serves A
// (direct) and B (transposed) reads.
__device__ __forceinline__ s16x8 load_frag(const short* buf, int row0,
                                           int kstep, int lane) {
  int m  = row0 + (lane & 15);
  int kg = kstep * 4 + (lane >> 4);
  return *(const s16x8*)(buf + m * 128 + ((kg ^ (m & 15)) << 3));
}

// ---------------------------------------------------------------------------
// The whole problem in one cooperative kernel: 192 blocks x 512 threads,
// 160 KiB LDS (1 block/CU, co-resident on 192 of 256 CUs).
// ---------------------------------------------------------------------------
__global__ __launch_bounds__(512, 2) void ole_all(const float* __restrict__ feat,
                                                  const int* __restrict__ y,
                                                  const float* __restrict__ logits,
                                                  float* __restrict__ G,
                                                  float* __restrict__ nuc,
                                                  float* __restrict__ cepart,
                                                  float* __restrict__ out) {
  __shared__ __align__(16) short smem[5 * DIM * DIM];   // 160 KiB

  cg::grid_group grid = cg::this_grid();

  const int bid  = blockIdx.x;
  const int tid  = threadIdx.x;
  const int lane = tid & 63;
  const int wv   = tid >> 6;       // 0..7

  // =========================== Phase 1 =================================
  if (bid < NCLS) {
    // ---- per-class Gram: 512 threads, 8x4 acc tile, 16-row batches ----
    int*  list = (int*)smem;                         // 32 KB
    float (*xs)[DIM] = (float (*)[DIM])(smem + 16384);  // 8 KB
    int*  cnt  = (int*)(smem + 20480);

    const int c  = bid;
    const int ti = tid >> 5;       // 0..15
    const int tj = tid & 31;       // 0..31
    const int i0 = ti * 8, j0 = tj * 4;

    if (tid == 0) *cnt = 0;
    __syncthreads();
    const int4* y4 = (const int4*)y;
#pragma unroll
    for (int t = 0; t < 4; ++t) {
      int g4 = tid + 512 * t;
      int4 v = y4[g4];
      int r0 = g4 * 4;
      if (v.x == c) list[atomicAdd(cnt, 1)] = r0;
      if (v.y == c) list[atomicAdd(cnt, 1)] = r0 + 1;
      if (v.z == c) list[atomicAdd(cnt, 1)] = r0 + 2;
      if (v.w == c) list[atomicAdd(cnt, 1)] = r0 + 3;
    }
    __syncthreads();
    const int n = *cnt;

    float acc[8][4];
#pragma unroll
    for (int a = 0; a < 8; ++a)
#pragma unroll
      for (int b = 0; b < 4; ++b) acc[a][b] = 0.f;

    for (int base = 0; base < n; base += 16) {
      __syncthreads();
      int li = base + (tid >> 5);
      float4 v = make_float4(0.f, 0.f, 0.f, 0.f);
      if (li < n) v = *(const float4*)(feat + (size_t)list[li] * DIM + (tid & 31) * 4);
      *(float4*)(&xs[tid >> 5][(tid & 31) * 4]) = v;
      __syncthreads();
#pragma unroll
      for (int rw = 0; rw < 16; ++rw) {
        float xi[8], xj[4];
#pragma unroll
        for (int a = 0; a < 8; ++a) xi[a] = xs[rw][i0 + a];
#pragma unroll
        for (int b = 0; b < 4; ++b) xj[b] = xs[rw][j0 + b];
#pragma unroll
        for (int a = 0; a < 8; ++a)
#pragma unroll
          for (int b = 0; b < 4; ++b) acc[a][b] = fmaf(xi[a], xj[b], acc[a][b]);
      }
    }

    float* Gc = G + (size_t)c * DIM * DIM;
#pragma unroll
    for (int a = 0; a < 8; ++a)
      *(float4*)(Gc + (i0 + a) * DIM + j0) =
        make_float4(acc[a][0], acc[a][1], acc[a][2], acc[a][3]);
  } else {
    // ---- cross-entropy: 128 blocks x 8 waves = 1024 waves, 8 rows each ----
    const int gwave = (bid - NCLS) * 8 + wv;
    float acc = 0.f;
    for (int row = gwave; row < N_ROWS; row += 1024) {
      float v = logits[row * NCLS + lane];
      float mx = v;
      for (int off = 32; off > 0; off >>= 1) mx = fmaxf(mx, __shfl_xor(mx, off, 64));
      float e = expf(v - mx);
      for (int off = 32; off > 0; off >>= 1) e += __shfl_xor(e, off, 64);
      if (lane == 0) {
        int t = y[row];
        acc += (mx + logf(e)) - logits[row * NCLS + t];
      }
    }
    if (lane == 0) cepart[gwave] = acc;
  }

  __threadfence();
  grid.sync();

  // =========================== Phase 2: Gall ===========================
  // Gall (matrix index 64, contiguous after the 64 class mats) = sum_c G_c.
  // Output w in [0,4096) float4s; w -> (block w%192, thread w/192).
  {
    const float4* G4 = (const float4*)G;
    if (tid < 22) {
      int w = bid + 192 * tid;
      if (w < DIM * DIM / 4) {
        float4 s = make_float4(0.f, 0.f, 0.f, 0.f);
#pragma unroll 8
        for (int c = 0; c < NCLS; ++c) {
          float4 v = G4[(size_t)c * (DIM * DIM / 4) + w];
          s.x += v.x; s.y += v.y; s.z += v.z; s.w += v.w;
        }
        ((float4*)G)[(size_t)NCLS * (DIM * DIM / 4) + w] = s;
      }
    }
  }

  __threadfence();
  grid.sync();

  // =========================== Phase 3: Newton-Schulz ==================
  if (bid < NMAT) {
    short* Yh = smem;
    short* Yl = smem + DIM * DIM;
    short* Mh = smem + 2 * DIM * DIM;
    short* Ml = smem + 3 * DIM * DIM;
    short* Zb = smem + 4 * DIM * DIM;

    const int quad = lane >> 4;
    const int wr   = wv >> 2;     // 0..1 -> tile-rows 4*wr..4*wr+3
    const int wc   = wv & 3;      // 0..3 -> tile-cols 2*wc..2*wc+1

    const float4* Gm4 = (const float4*)(G + (size_t)bid * DIM * DIM);

    // ---- load G (8 float4/thread), in-block trace + fro2 ----
    float4 gs[8];
    float tpart = 0.f, fpart = 0.f;
#pragma unroll
    for (int t = 0; t < 8; ++t) {
      int idx4 = tid + 512 * t;
      float4 v = Gm4[idx4];
      gs[t] = v;
      fpart += v.x * v.x + v.y * v.y + v.z * v.z + v.w * v.w;
      int flat = idx4 * 4, i = flat >> 7, j0 = flat & 127;
      if (j0 <= i && i < j0 + 4) tpart += ((const float*)&v)[i - j0];
    }
    for (int off = 32; off > 0; off >>= 1) {
      tpart += __shfl_down(tpart, off, 64);
      fpart += __shfl_down(fpart, off, 64);
    }
    float* redf = (float*)Zb;           // Zb not yet initialized
    if (lane == 0) { redf[wv] = tpart; redf[8 + wv] = fpart; }
    __syncthreads();
    float trace = 0.f, fro2 = 0.f;
#pragma unroll
    for (int w = 0; w < 8; ++w) { trace += redf[w]; fro2 += redf[8 + w]; }
    __syncthreads();                    // redf reads done -> Zb reusable

    float s = sqrtf(fro2);
    if (s < 1e-12f) s = 1.f;
    const float invs = 1.f / s;
    const float eps  = EPSN * trace * invs;

    // ---- init: Y0 = G/s + eps*I (hi/lo), Z0 = I ----
#pragma unroll
    for (int t = 0; t < 8; ++t) {
      int idx4 = tid + 512 * t;
      int flat = idx4 * 4, i = flat >> 7, j0 = flat & 127;
      s16x4 vh, vl;
#pragma unroll
      for (int e = 0; e < 4; ++e) {
        float x = ((const float*)&gs[t])[e] * invs + ((i == j0 + e) ? eps : 0.f);
        unsigned short hh = f2bf(x);
        vh[e] = (short)hh;
        vl[e] = (short)f2bf(x - bf2f(hh));
      }
      int idx = swz_idx(i, j0);
      *(s16x4*)(Yh + idx) = vh;
      *(s16x4*)(Yl + idx) = vl;
    }
    for (int grp = tid; grp < DIM * 16; grp += 512) {
      int i = grp >> 4, g = grp & 15;
      s16x8 v = (s16x8)0;
      if ((i >> 3) == g) v[i & 7] = (short)0x3F80;   // 1.0 bf16
      *(s16x8*)(Zb + i * 128 + ((g ^ (i & 15)) << 3)) = v;
    }
    __syncthreads();

    for (int it = 0; it < NITER; ++it) {
      const float kA = NS_C1[it];
      const float kB = NS_C2[it];

      // --- (a) W = Z*Y (Yh+Yl) ---
      f32x4 acc[4][2];
#pragma unroll
      for (int r = 0; r < 4; ++r)
#pragma unroll
        for (int c2 = 0; c2 < 2; ++c2) acc[r][c2] = (f32x4)0.f;
#pragma unroll
      for (int ks = 0; ks < 4; ++ks) {
        s16x8 a[4], bh[2], bl[2];
#pragma unroll
        for (int r = 0; r < 4; ++r) a[r] = load_frag(Zb, (4 * wr + r) * 16, ks, lane);
#pragma unroll
        for (int c2 = 0; c2 < 2; ++c2) {
          bh[c2] = load_frag(Yh, (2 * wc + c2) * 16, ks, lane);
          bl[c2] = load_frag(Yl, (2 * wc + c2) * 16, ks, lane);
        }
#pragma unroll
        for (int r = 0; r < 4; ++r)
#pragma unroll
          for (int c2 = 0; c2 < 2; ++c2) {
            acc[r][c2] = __builtin_amdgcn_mfma_f32_16x16x32_bf16(a[r], bh[c2], acc[r][c2], 0, 0, 0);
            acc[r][c2] = __builtin_amdgcn_mfma_f32_16x16x32_bf16(a[r], bl[c2], acc[r][c2], 0, 0, 0);
          }
      }
      // --- (b) M = kA*I - kB*W, clamp, hi/lo split, transposed store ---
#pragma unroll
      for (int r = 0; r < 4; ++r) {
        int ibase = (4 * wr + r) * 16 + quad * 4;
        int cg    = ibase >> 3;
#pragma unroll
        for (int c2 = 0; c2 < 2; ++c2) {
          int jg  = (2 * wc + c2) * 16 + (lane & 15);
          int idx = jg * 128 + ((cg ^ (jg & 15)) << 3) + (ibase & 7);
          s16x4 vh, vl;
#pragma unroll
          for (int e = 0; e < 4; ++e) {
            float mv = -kB * acc[r][c2][e] + ((ibase + e == jg) ? kA : 0.f);
            mv = fminf(fmaxf(mv, -4.f), 4.f);        // runaway insurance
            unsigned short hh = f2bf(mv);
            vh[e] = (short)hh;
            vl[e] = (short)f2bf(mv - bf2f(hh));
          }
          *(s16x4*)(Mh + idx) = vh;
          *(s16x4*)(Ml + idx) = vl;
        }
      }
      __syncthreads();

      // --- (c) Y' = M*Y, Z' = M*Z: M is the SHARED A operand (iterates
      //     commute, so M*Y == Y*M).  5 products, A-frags read once. ---
      f32x4 ay[4][2], az[4][2];
#pragma unroll
      for (int r = 0; r < 4; ++r)
#pragma unroll
        for (int c2 = 0; c2 < 2; ++c2) { ay[r][c2] = (f32x4)0.f; az[r][c2] = (f32x4)0.f; }
#pragma unroll
      for (int ks = 0; ks < 4; ++ks) {
        s16x8 aMh[4], aMl[4], bYh[2], bYl[2], bZ[2];
#pragma unroll
        for (int r = 0; r < 4; ++r) {
          int rb = (4 * wr + r) * 16;
          aMh[r] = load_frag(Mh, rb, ks, lane);
          aMl[r] = load_frag(Ml, rb, ks, lane);
        }
#pragma unroll
        for (int c2 = 0; c2 < 2; ++c2) {
          int cb = (2 * wc + c2) * 16;
          bYh[c2] = load_frag(Yh, cb, ks, lane);
          bYl[c2] = load_frag(Yl, cb, ks, lane);
          bZ[c2]  = load_frag(Zb, cb, ks, lane);
        }
#pragma unroll
        for (int r = 0; r < 4; ++r)
#pragma unroll
          for (int c2 = 0; c2 < 2; ++c2) {
            ay[r][c2] = __builtin_amdgcn_mfma_f32_16x16x32_bf16(aMh[r], bYh[c2], ay[r][c2], 0, 0, 0);
            ay[r][c2] = __builtin_amdgcn_mfma_f32_16x16x32_bf16(aMh[r], bYl[c2], ay[r][c2], 0, 0, 0);
            ay[r][c2] = __builtin_amdgcn_mfma_f32_16x16x32_bf16(aMl[r], bYh[c2], ay[r][c2], 0, 0, 0);
            az[r][c2] = __builtin_amdgcn_mfma_f32_16x16x32_bf16(aMh[r], bZ[c2],  az[r][c2], 0, 0, 0);
            az[r][c2] = __builtin_amdgcn_mfma_f32_16x16x32_bf16(aMl[r], bZ[c2],  az[r][c2], 0, 0, 0);
          }
      }
      __syncthreads();   // all reads of Y,Z done

      // --- (d) store Y' (hi/lo), Z' (single), transposed ---
#pragma unroll
      for (int r = 0; r < 4; ++r) {
        int ibase = (4 * wr + r) * 16 + quad * 4;
        int cg    = ibase >> 3;
#pragma unroll
        for (int c2 = 0; c2 < 2; ++c2) {
          int jg  = (2 * wc + c2) * 16 + (lane & 15);
          int idx = jg * 128 + ((cg ^ (jg & 15)) << 3) + (ibase & 7);
          s16x4 vh, vl, vz;
#pragma unroll
          for (int e = 0; e < 4; ++e) {
            float yv = ay[r][c2][e];
            unsigned short hh = f2bf(yv);
            vh[e] = (short)hh;
            vl[e] = (short)f2bf(yv - bf2f(hh));
            vz[e] = (short)f2bf(az[r][c2][e]);
          }
          *(s16x4*)(Yh + idx) = vh;
          *(s16x4*)(Yl + idx) = vl;
          *(s16x4*)(Zb + idx) = vz;
        }
      }
      __syncthreads();
    }

    // ---- traces: tr(GZ) (fp32 G anchor), tr(Z), tr(Z^3) ----
    float t_gz = 0.f, t_z = 0.f, t_z3 = 0.f;
#pragma unroll
    for (int t = 0; t < 8; ++t) {
      int idx4 = tid + 512 * t;
      int flat = idx4 * 4, i = flat >> 7, j0 = flat & 127;
      s16x4 zv = *(const s16x4*)(Zb + swz_idx(i, j0));
#pragma unroll
      for (int e = 0; e < 4; ++e) t_gz += ((const float*)&gs[t])[e] * bf2f((unsigned short)zv[e]);
    }
    if (tid < DIM) t_z = bf2f((unsigned short)Zb[swz_idx(tid, tid)]);

    {  // U = Z*Z tile-wise; tr(Z^3) = sum U_ij * Z_ji
      f32x4 u[4][2];
#pragma unroll
      for (int r = 0; r < 4; ++r)
#pragma unroll
        for (int c2 = 0; c2 < 2; ++c2) u[r][c2] = (f32x4)0.f;
#pragma unroll
      for (int ks = 0; ks < 4; ++ks) {
        s16x8 a[4], b[2];
#pragma unroll
        for (int r = 0; r < 4; ++r) a[r] = load_frag(Zb, (4 * wr + r) * 16, ks, lane);
#pragma unroll
        for (int c2 = 0; c2 < 2; ++c2) b[c2] = load_frag(Zb, (2 * wc + c2) * 16, ks, lane);
#pragma unroll
        for (int r = 0; r < 4; ++r)
#pragma unroll
          for (int c2 = 0; c2 < 2; ++c2)
            u[r][c2] = __builtin_amdgcn_mfma_f32_16x16x32_bf16(a[r], b[c2], u[r][c2], 0, 0, 0);
      }
#pragma unroll
      for (int r = 0; r < 4; ++r) {
        int ibase = (4 * wr + r) * 16 + quad * 4;
        int cg    = ibase >> 3;
#pragma unroll
        for (int c2 = 0; c2 < 2; ++c2) {
          int jg  = (2 * wc + c2) * 16 + (lane & 15);
          int idx = jg * 128 + ((cg ^ (jg & 15)) << 3) + (ibase & 7);
          s16x4 zt = *(const s16x4*)(Zb + idx);
#pragma unroll
          for (int e = 0; e < 4; ++e) t_z3 += u[r][c2][e] * bf2f((unsigned short)zt[e]);
        }
      }
    }

    for (int off = 32; off > 0; off >>= 1) {
      t_gz += __shfl_down(t_gz, off, 64);
      t_z  += __shfl_down(t_z,  off, 64);
      t_z3 += __shfl_down(t_z3, off, 64);
    }
    __syncthreads();
    float* red = (float*)Mh;
    if (lane == 0) { red[wv] = t_gz; red[8 + wv] = t_z; red[16 + wv] = t_z3; }
    __syncthreads();
    if (tid == 0) {
      float gz = 0.f, z1 = 0.f, z3 = 0.f;
#pragma unroll
      for (int w = 0; w < 8; ++w) { gz += red[w]; z1 += red[8 + w]; z3 += red[16 + w]; }
      float trsq = gz * invs + 0.5f * eps * z1 - 0.125f * eps * eps * z3;
      nuc[bid] = sqrtf(s) * trsq;
    }
  }

  __threadfence();
  grid.sync();

  // =========================== Phase 4: final ==========================
  if (bid == 0) {
    float ce = cepart[tid] + cepart[tid + 512];
    float v  = (tid < NCLS) ? fmaxf(nuc[tid], DELTA_) : 0.f;
    for (int off = 32; off > 0; off >>= 1) {
      v  += __shfl_down(v,  off, 64);
      ce += __shfl_down(ce, off, 64);
    }
    float* red = (float*)smem;
    if (lane == 0) { red[wv] = v; red[8 + wv] = ce; }
    __syncthreads();
    if (tid == 0) {
      float vs = 0.f, cs = 0.f;
#pragma unroll
      for (int w = 0; w < 8; ++w) { vs += red[w]; cs += red[8 + w]; }
      float ole = (vs - nuc[NCLS]) * (LAMBDA_ / (float)N_ROWS);
      out[0] = ole + cs / (float)N_ROWS;
    }
  }
}

extern "C" void kernel_launch(void* const* d_in, const int* in_sizes, int n_in,
                              void* d_out, int out_size, void* d_ws, size_t ws_size,
                              hipStream_t stream) {
  const float* logits = (const float*)d_in[0];   // out  [8192,64]
  const float* feat   = (const float*)d_in[1];   // feat [8192,128]
  const int*   yp     = (const int*)d_in[2];     // y    [8192]

  float* G      = (float*)d_ws;                  // 64 class mats + Gall (idx 64)
  float* nuc    = G + (size_t)NMAT * DIM * DIM;  // 65 floats
  float* cepart = nuc + NMAT + 3;                // 1024 floats
  float* outp   = (float*)d_out;

  void* args[] = {(void*)&feat, (void*)&yp, (void*)&logits,
                  (void*)&G, (void*)&nuc, (void*)&cepart, (void*)&outp};
  hipLaunchCooperativeKernel((const void*)ole_all, dim3(192), dim3(512),
                             args, 0, stream);
}

// Round 10
// 175.136 us; speedup vs baseline: 1.7230x; 1.7230x over previous
//
#include <hip/hip_runtime.h>
#include <math.h>

// OLE loss on MI355X.
// ||X_c||* = trace(sqrt(G_c)), G_c = X_c^T X_c (128x128).
// Coupled Newton-Schulz on bf16 MFMA, one block per matrix.
// Y,M split bf16 (hi+lo ~2^-17), Z single bf16; Frobenius normalization;
// scaled-NS ladder (9 iters); trace anchored on fp32 G.
// R10 = R9 with the 4-byte LDS overflow fixed (lastflag lives in Mh scratch).
// Kernel A: gram blocks signal done-counter, CE blocks spin (co-resident:
// 192 blocks <= 256 CUs) then build Gall.  Kernel B: NS with shared-A
// phase (c) + last-arriving-block final combine.
// (R8 lesson: cooperative grid.sync costs ~50us/barrier on 8 XCDs — avoid.)

#define N_ROWS 8192
#define DIM    128
#define NCLS   64
#define NMAT   65
#define NITER  9
#define EPSN   2e-4f
#define LAMBDA_ 0.25f
#define DELTA_  1.0f

typedef __attribute__((ext_vector_type(8))) short s16x8;  // 8 bf16 = 4 VGPR
typedef __attribute__((ext_vector_type(4))) short s16x4;  // 4 bf16
typedef __attribute__((ext_vector_type(4))) float f32x4;

// Scaled-NS ladder: M_k = C1[k]*I - C2[k]*W, C1 = 1.5*sqrt(t), C2 = 0.5*t^1.5.
// t = [2.9, 2.758, 2.13, 1.868, 1.264, 1,1,1,1]; u = t*w, w' = u(1.5-u/2)^2
// stays in (0,1] for u in (0,3) -> sign-safe; final t=1 steps polish w->1.
static __device__ const float NS_C1[NITER] =
  {2.554408f, 2.491084f, 2.189178f, 2.050122f, 1.686417f, 1.5f, 1.5f, 1.5f, 1.5f};
static __device__ const float NS_C2[NITER] =
  {2.469261f, 2.290137f, 1.554316f, 1.276543f, 0.710544f, 0.5f, 0.5f, 0.5f, 0.5f};

__device__ __forceinline__ unsigned short f2bf(float f) {   // RNE
  unsigned u = __float_as_uint(f);
  u = (u + 0x7FFFu + ((u >> 16) & 1u)) >> 16;
  return (unsigned short)u;
}
__device__ __forceinline__ float bf2f(unsigned short h) {
  return __uint_as_float(((unsigned)h) << 16);
}

// bf16 LDS: element (i,j) at short-index i*128 + (((j>>3)^(i&15))<<3) + (j&7)
// 16B-group XOR swizzle -> all b128/b64 frag accesses 2-way per bank (free).
__device__ __forceinline__ int swz_idx(int i, int j) {
  return i * 128 + (((j >> 3) ^ (i & 15)) << 3) + (j & 7);
}

// MFMA 16x16x32 A/B fragment: lane holds 8 contiguous k at row (lane&15),
// kgroup = 4*kstep + (lane>>4).  Symmetric iterates: same loader serves A
// (direct) and B (transposed) reads.
__device__ __forceinline__ s16x8 load_frag(const short* buf, int row0,
                                           int kstep, int lane) {
  int m  = row0 + (lane & 15);
  int kg = kstep * 4 + (lane >> 4);
  return *(const s16x8*)(buf + m * 128 + ((kg ^ (m & 15)) << 3));
}

// ---------------------------------------------------------------------------
// Kernel A: blocks 0..63 = per-class Gram (signal gram_done); blocks
// 64..191 = cross-entropy, then wait for gram_done==64, then Gall slices.
// 192 blocks x 256 thr, <=40KB LDS -> all co-resident (spin is safe).
// ---------------------------------------------------------------------------
__global__ __launch_bounds__(256) void ole_gram_ce(const float* __restrict__ feat,
                                                   const int* __restrict__ y,
                                                   const float* __restrict__ logits,
                                                   float* __restrict__ G,
                                                   float* __restrict__ cepart,
                                                   int* __restrict__ ctr) {
  __shared__ int   list[N_ROWS];
  __shared__ int   cnt;
  __shared__ float xs[8][DIM];

  const int tid = threadIdx.x;

  if (blockIdx.x >= NCLS) {
    // ---------------- CE path (128 blocks, 512 waves) ----------------
    const int blk    = blockIdx.x - NCLS;
    const int gwave  = blk * 4 + (tid >> 6);
    const int lane   = tid & 63;

    float acc = 0.f;
    for (int row = gwave; row < N_ROWS; row += 512) {
      float v = logits[row * NCLS + lane];
      float mx = v;
      for (int off = 32; off > 0; off >>= 1) mx = fmaxf(mx, __shfl_xor(mx, off, 64));
      float e = expf(v - mx);
      for (int off = 32; off > 0; off >>= 1) e += __shfl_xor(e, off, 64);
      if (lane == 0) {
        int t = y[row];
        acc += (mx + logf(e)) - logits[row * NCLS + t];
      }
    }
    if (lane == 0) cepart[gwave] = acc;

    // ---- wait for all gram blocks, then build Gall slice ----
    if (tid == 0) {
      while (__hip_atomic_load(ctr, __ATOMIC_ACQUIRE,
                               __HIP_MEMORY_SCOPE_AGENT) < NCLS)
        __builtin_amdgcn_s_sleep(32);
    }
    __syncthreads();
    if (tid < 32) {
      int idx4 = blk * 32 + tid;          // 128 blocks x 32 = 4096 float4s
      const float4* G4 = (const float4*)G;
      float4 s = make_float4(0.f, 0.f, 0.f, 0.f);
#pragma unroll 8
      for (int c = 0; c < NCLS; ++c) {
        float4 v = G4[(size_t)c * (DIM * DIM / 4) + idx4];
        s.x += v.x; s.y += v.y; s.z += v.z; s.w += v.w;
      }
      ((float4*)G)[(size_t)NCLS * (DIM * DIM / 4) + idx4] = s;
    }
    return;
  }

  // ---------------- gram path (64 blocks) ----------------
  const int c  = blockIdx.x;
  const int ti = tid >> 4, tj = tid & 15;
  const int i0 = ti * 8,  j0 = tj * 8;

  if (tid == 0) cnt = 0;
  __syncthreads();
  const int4* y4 = (const int4*)y;
#pragma unroll
  for (int t = 0; t < 8; ++t) {
    int g4 = tid + 256 * t;
    int4 v = y4[g4];
    int r0 = g4 * 4;
    if (v.x == c) list[atomicAdd(&cnt, 1)] = r0;
    if (v.y == c) list[atomicAdd(&cnt, 1)] = r0 + 1;
    if (v.z == c) list[atomicAdd(&cnt, 1)] = r0 + 2;
    if (v.w == c) list[atomicAdd(&cnt, 1)] = r0 + 3;
  }
  __syncthreads();
  const int n = cnt;

  float acc[8][8];
#pragma unroll
  for (int a = 0; a < 8; ++a)
#pragma unroll
    for (int b = 0; b < 8; ++b) acc[a][b] = 0.f;

  const int ldrow = tid >> 5;
  const int ldcol = (tid & 31) * 4;

  for (int base = 0; base < n; base += 8) {
    __syncthreads();
    int li = base + ldrow;
    float4 v = make_float4(0.f, 0.f, 0.f, 0.f);
    if (li < n) v = *(const float4*)(feat + (size_t)list[li] * DIM + ldcol);
    *(float4*)(&xs[ldrow][ldcol]) = v;
    __syncthreads();
#pragma unroll
    for (int rw = 0; rw < 8; ++rw) {
      float xi[8], xj[8];
#pragma unroll
      for (int a = 0; a < 8; ++a) xi[a] = xs[rw][i0 + a];
#pragma unroll
      for (int b = 0; b < 8; ++b) xj[b] = xs[rw][j0 + b];
#pragma unroll
      for (int a = 0; a < 8; ++a)
#pragma unroll
        for (int b = 0; b < 8; ++b) acc[a][b] = fmaf(xi[a], xj[b], acc[a][b]);
    }
  }

  float* Gc = G + (size_t)c * DIM * DIM;
#pragma unroll
  for (int a = 0; a < 8; ++a)
#pragma unroll
    for (int b = 0; b < 8; ++b)
      Gc[(i0 + a) * DIM + (j0 + b)] = acc[a][b];

  __syncthreads();
  if (tid == 0) {
    __threadfence();                       // G_c visible before signal
    __hip_atomic_fetch_add(ctr, 1, __ATOMIC_RELEASE, __HIP_MEMORY_SCOPE_AGENT);
  }
}

// ---------------------------------------------------------------------------
// Kernel B: scaled Newton-Schulz (one block/matrix, 512 thr, 8 waves,
// 2x4 wave grid) + last-arriving-block final combine.
// LDS = exactly 5*32KB = 160 KiB; all scratch (reductions, lastflag)
// lives inside Mh after its last use.
// ---------------------------------------------------------------------------
__global__ __launch_bounds__(512, 1) void ole_ns(const float* __restrict__ G,
                                                 float* __restrict__ nuc,
                                                 const float* __restrict__ cepart,
                                                 int* __restrict__ ctr,
                                                 float* __restrict__ out) {
  __shared__ short Yh[DIM * DIM];
  __shared__ short Yl[DIM * DIM];
  __shared__ short Mh[DIM * DIM];
  __shared__ short Ml[DIM * DIM];
  __shared__ short Zb[DIM * DIM];

  const int m_id = blockIdx.x;
  const int tid  = threadIdx.x;
  const int lane = tid & 63;
  const int quad = lane >> 4;
  const int wv   = tid >> 6;    // 0..7
  const int wr   = wv >> 2;     // 0..1 -> tile-rows 4*wr..4*wr+3
  const int wc   = wv & 3;      // 0..3 -> tile-cols 2*wc..2*wc+1

  const float4* Gm4 = (const float4*)(G + (size_t)m_id * DIM * DIM);

  // ---- load G (8 float4/thread), in-block trace + fro2 ----
  float4 gs[8];
  float tpart = 0.f, fpart = 0.f;
#pragma unroll
  for (int t = 0; t < 8; ++t) {
    int idx4 = tid + 512 * t;
    float4 v = Gm4[idx4];
    gs[t] = v;
    fpart += v.x * v.x + v.y * v.y + v.z * v.z + v.w * v.w;
    int flat = idx4 * 4, i = flat >> 7, j0 = flat & 127;
    if (j0 <= i && i < j0 + 4) tpart += ((const float*)&v)[i - j0];
  }
  for (int off = 32; off > 0; off >>= 1) {
    tpart += __shfl_down(tpart, off, 64);
    fpart += __shfl_down(fpart, off, 64);
  }
  float* redf = (float*)Zb;           // Zb not yet initialized
  if (lane == 0) { redf[wv] = tpart; redf[8 + wv] = fpart; }
  __syncthreads();
  float trace = 0.f, fro2 = 0.f;
#pragma unroll
  for (int w = 0; w < 8; ++w) { trace += redf[w]; fro2 += redf[8 + w]; }
  __syncthreads();                    // redf reads done -> Zb reusable

  float s = sqrtf(fro2);
  if (s < 1e-12f) s = 1.f;
  const float invs = 1.f / s;
  const float eps  = EPSN * trace * invs;

  // ---- init: Y0 = G/s + eps*I (hi/lo), Z0 = I ----
#pragma unroll
  for (int t = 0; t < 8; ++t) {
    int idx4 = tid + 512 * t;
    int flat = idx4 * 4, i = flat >> 7, j0 = flat & 127;
    s16x4 vh, vl;
#pragma unroll
    for (int e = 0; e < 4; ++e) {
      float x = ((const float*)&gs[t])[e] * invs + ((i == j0 + e) ? eps : 0.f);
      unsigned short hh = f2bf(x);
      vh[e] = (short)hh;
      vl[e] = (short)f2bf(x - bf2f(hh));
    }
    int idx = swz_idx(i, j0);
    *(s16x4*)(Yh + idx) = vh;
    *(s16x4*)(Yl + idx) = vl;
  }
  for (int grp = tid; grp < DIM * 16; grp += 512) {
    int i = grp >> 4, g = grp & 15;
    s16x8 v = (s16x8)0;
    if ((i >> 3) == g) v[i & 7] = (short)0x3F80;   // 1.0 bf16
    *(s16x8*)(Zb + i * 128 + ((g ^ (i & 15)) << 3)) = v;
  }
  __syncthreads();

  for (int it = 0; it < NITER; ++it) {
    const float kA = NS_C1[it];
    const float kB = NS_C2[it];

    // --- (a) W = Z*Y (Yh+Yl) ---
    f32x4 acc[4][2];
#pragma unroll
    for (int r = 0; r < 4; ++r)
#pragma unroll
      for (int c2 = 0; c2 < 2; ++c2) acc[r][c2] = (f32x4)0.f;
#pragma unroll
    for (int ks = 0; ks < 4; ++ks) {
      s16x8 a[4], bh[2], bl[2];
#pragma unroll
      for (int r = 0; r < 4; ++r) a[r] = load_frag(Zb, (4 * wr + r) * 16, ks, lane);
#pragma unroll
      for (int c2 = 0; c2 < 2; ++c2) {
        bh[c2] = load_frag(Yh, (2 * wc + c2) * 16, ks, lane);
        bl[c2] = load_frag(Yl, (2 * wc + c2) * 16, ks, lane);
      }
#pragma unroll
      for (int r = 0; r < 4; ++r)
#pragma unroll
        for (int c2 = 0; c2 < 2; ++c2) {
          acc[r][c2] = __builtin_amdgcn_mfma_f32_16x16x32_bf16(a[r], bh[c2], acc[r][c2], 0, 0, 0);
          acc[r][c2] = __builtin_amdgcn_mfma_f32_16x16x32_bf16(a[r], bl[c2], acc[r][c2], 0, 0, 0);
        }
    }
    // --- (b) M = kA*I - kB*W, clamp, hi/lo split, transposed store ---
#pragma unroll
    for (int r = 0; r < 4; ++r) {
      int ibase = (4 * wr + r) * 16 + quad * 4;
      int cg    = ibase >> 3;
#pragma unroll
      for (int c2 = 0; c2 < 2; ++c2) {
        int jg  = (2 * wc + c2) * 16 + (lane & 15);
        int idx = jg * 128 + ((cg ^ (jg & 15)) << 3) + (ibase & 7);
        s16x4 vh, vl;
#pragma unroll
        for (int e = 0; e < 4; ++e) {
          float mv = -kB * acc[r][c2][e] + ((ibase + e == jg) ? kA : 0.f);
          mv = fminf(fmaxf(mv, -4.f), 4.f);        // runaway insurance
          unsigned short hh = f2bf(mv);
          vh[e] = (short)hh;
          vl[e] = (short)f2bf(mv - bf2f(hh));
        }
        *(s16x4*)(Mh + idx) = vh;
        *(s16x4*)(Ml + idx) = vl;
      }
    }
    __syncthreads();

    // --- (c) Y' = M*Y, Z' = M*Z: M is the SHARED A operand (iterates
    //     commute so M*Y == Y*M).  A-frags read once for 5 products. ---
    f32x4 ay[4][2], az[4][2];
#pragma unroll
    for (int r = 0; r < 4; ++r)
#pragma unroll
      for (int c2 = 0; c2 < 2; ++c2) { ay[r][c2] = (f32x4)0.f; az[r][c2] = (f32x4)0.f; }
#pragma unroll
    for (int ks = 0; ks < 4; ++ks) {
      s16x8 aMh[4], aMl[4], bYh[2], bYl[2], bZ[2];
#pragma unroll
      for (int r = 0; r < 4; ++r) {
        int rb = (4 * wr + r) * 16;
        aMh[r] = load_frag(Mh, rb, ks, lane);
        aMl[r] = load_frag(Ml, rb, ks, lane);
      }
#pragma unroll
      for (int c2 = 0; c2 < 2; ++c2) {
        int cb = (2 * wc + c2) * 16;
        bYh[c2] = load_frag(Yh, cb, ks, lane);
        bYl[c2] = load_frag(Yl, cb, ks, lane);
        bZ[c2]  = load_frag(Zb, cb, ks, lane);
      }
#pragma unroll
      for (int r = 0; r < 4; ++r)
#pragma unroll
        for (int c2 = 0; c2 < 2; ++c2) {
          ay[r][c2] = __builtin_amdgcn_mfma_f32_16x16x32_bf16(aMh[r], bYh[c2], ay[r][c2], 0, 0, 0);
          ay[r][c2] = __builtin_amdgcn_mfma_f32_16x16x32_bf16(aMh[r], bYl[c2], ay[r][c2], 0, 0, 0);
          ay[r][c2] = __builtin_amdgcn_mfma_f32_16x16x32_bf16(aMl[r], bYh[c2], ay[r][c2], 0, 0, 0);
          az[r][c2] = __builtin_amdgcn_mfma_f32_16x16x32_bf16(aMh[r], bZ[c2],  az[r][c2], 0, 0, 0);
          az[r][c2] = __builtin_amdgcn_mfma_f32_16x16x32_bf16(aMl[r], bZ[c2],  az[r][c2], 0, 0, 0);
        }
    }
    __syncthreads();   // all reads of Y,Z done

    // --- (d) store Y' (hi/lo), Z' (single), transposed ---
#pragma unroll
    for (int r = 0; r < 4; ++r) {
      int ibase = (4 * wr + r) * 16 + quad * 4;
      int cg    = ibase >> 3;
#pragma unroll
      for (int c2 = 0; c2 < 2; ++c2) {
        int jg  = (2 * wc + c2) * 16 + (lane & 15);
        int idx = jg * 128 + ((cg ^ (jg & 15)) << 3) + (ibase & 7);
        s16x4 vh, vl, vz;
#pragma unroll
        for (int e = 0; e < 4; ++e) {
          float yv = ay[r][c2][e];
          unsigned short hh = f2bf(yv);
          vh[e] = (short)hh;
          vl[e] = (short)f2bf(yv - bf2f(hh));
          vz[e] = (short)f2bf(az[r][c2][e]);
        }
        *(s16x4*)(Yh + idx) = vh;
        *(s16x4*)(Yl + idx) = vl;
        *(s16x4*)(Zb + idx) = vz;
      }
    }
    __syncthreads();
  }

  // ---- traces: tr(GZ) (fp32 G anchor), tr(Z), tr(Z^3) ----
  float t_gz = 0.f, t_z = 0.f, t_z3 = 0.f;
#pragma unroll
  for (int t = 0; t < 8; ++t) {
    int idx4 = tid + 512 * t;
    int flat = idx4 * 4, i = flat >> 7, j0 = flat & 127;
    s16x4 zv = *(const s16x4*)(Zb + swz_idx(i, j0));
#pragma unroll
    for (int e = 0; e < 4; ++e) t_gz += ((const float*)&gs[t])[e] * bf2f((unsigned short)zv[e]);
  }
  if (tid < DIM) t_z = bf2f((unsigned short)Zb[swz_idx(tid, tid)]);

  {  // U = Z*Z tile-wise; tr(Z^3) = sum U_ij * Z_ji
    f32x4 u[4][2];
#pragma unroll
    for (int r = 0; r < 4; ++r)
#pragma unroll
      for (int c2 = 0; c2 < 2; ++c2) u[r][c2] = (f32x4)0.f;
#pragma unroll
    for (int ks = 0; ks < 4; ++ks) {
      s16x8 a[4], b[2];
#pragma unroll
      for (int r = 0; r < 4; ++r) a[r] = load_frag(Zb, (4 * wr + r) * 16, ks, lane);
#pragma unroll
      for (int c2 = 0; c2 < 2; ++c2) b[c2] = load_frag(Zb, (2 * wc + c2) * 16, ks, lane);
#pragma unroll
      for (int r = 0; r < 4; ++r)
#pragma unroll
        for (int c2 = 0; c2 < 2; ++c2)
          u[r][c2] = __builtin_amdgcn_mfma_f32_16x16x32_bf16(a[r], b[c2], u[r][c2], 0, 0, 0);
    }
#pragma unroll
    for (int r = 0; r < 4; ++r) {
      int ibase = (4 * wr + r) * 16 + quad * 4;
      int cg    = ibase >> 3;
#pragma unroll
      for (int c2 = 0; c2 < 2; ++c2) {
        int jg  = (2 * wc + c2) * 16 + (lane & 15);
        int idx = jg * 128 + ((cg ^ (jg & 15)) << 3) + (ibase & 7);
        s16x4 zt = *(const s16x4*)(Zb + idx);
#pragma unroll
        for (int e = 0; e < 4; ++e) t_z3 += u[r][c2][e] * bf2f((unsigned short)zt[e]);
      }
    }
  }

  for (int off = 32; off > 0; off >>= 1) {
    t_gz += __shfl_down(t_gz, off, 64);
    t_z  += __shfl_down(t_z,  off, 64);
    t_z3 += __shfl_down(t_z3, off, 64);
  }
  __syncthreads();
  float* red      = (float*)Mh;        // Mh dead after last iter
  int*   lastflag = (int*)(Mh + 64);   // scratch slot, not a new LDS alloc
  if (lane == 0) { red[wv] = t_gz; red[8 + wv] = t_z; red[16 + wv] = t_z3; }
  __syncthreads();
  if (tid == 0) {
    float gz = 0.f, z1 = 0.f, z3 = 0.f;
#pragma unroll
    for (int w = 0; w < 8; ++w) { gz += red[w]; z1 += red[8 + w]; z3 += red[16 + w]; }
    float trsq = gz * invs + 0.5f * eps * z1 - 0.125f * eps * eps * z3;
    nuc[m_id] = sqrtf(s) * trsq;

    // signal completion; detect last block (counter pre-zeroed by memset)
    __threadfence();
    int old = __hip_atomic_fetch_add(ctr, 1, __ATOMIC_ACQ_REL,
                                     __HIP_MEMORY_SCOPE_AGENT);
    *lastflag = (old == NMAT - 1);
  }
  __syncthreads();

  // ---- last-arriving block: final combine ----
  if (*lastflag) {
    float ce = cepart[tid];
    float v  = (tid < NCLS) ? fmaxf(nuc[tid], DELTA_) : 0.f;
    for (int off = 32; off > 0; off >>= 1) {
      v  += __shfl_down(v,  off, 64);
      ce += __shfl_down(ce, off, 64);
    }
    if (lane == 0) { red[wv] = v; red[8 + wv] = ce; }
    __syncthreads();
    if (tid == 0) {
      float vs = 0.f, cs = 0.f;
#pragma unroll
      for (int w = 0; w < 8; ++w) { vs += red[w]; cs += red[8 + w]; }
      float ole = (vs - nuc[NCLS]) * (LAMBDA_ / (float)N_ROWS);
      out[0] = ole + cs / (float)N_ROWS;
    }
  }
}

extern "C" void kernel_launch(void* const* d_in, const int* in_sizes, int n_in,
                              void* d_out, int out_size, void* d_ws, size_t ws_size,
                              hipStream_t stream) {
  const float* logits = (const float*)d_in[0];   // out  [8192,64]
  const float* feat   = (const float*)d_in[1];   // feat [8192,128]
  const int*   yp     = (const int*)d_in[2];     // y    [8192]

  float* G      = (float*)d_ws;                  // 64 class mats + Gall (idx 64)
  float* nuc    = G + (size_t)NMAT * DIM * DIM;  // 65 floats (+3 pad)
  float* cepart = nuc + NMAT + 3;                // 512 floats
  int*   ctrs   = (int*)(cepart + 512);          // [0]=gram_done, [1]=ns_done

  (void)hipMemsetAsync(ctrs, 0, 2 * sizeof(int), stream);
  ole_gram_ce<<<NCLS + 128, 256, 0, stream>>>(feat, yp, logits, G, cepart, ctrs);
  ole_ns<<<NMAT, 512, 0, stream>>>(G, nuc, cepart, ctrs + 1, (float*)d_out);
}